// Round 3
// baseline (1188.328 us; speedup 1.0000x reference)
//
#include <hip/hip_runtime.h>
#include <hip/hip_bf16.h>
#include <stdint.h>

#define Bn 256
#define Tn 512
#define Hn 128
#define G4 512   // 4*H
#define Mn (Bn*Tn)

typedef __attribute__((ext_vector_type(8))) short s16x8;
typedef __attribute__((ext_vector_type(4))) float f32x4;

__device__ __forceinline__ float b2f(unsigned short u) {
    union { unsigned int i; float f; } v; v.i = ((unsigned int)u) << 16; return v.f;
}
__device__ __forceinline__ unsigned short f2b(float f) {
    union { float f; unsigned int i; } v; v.f = f;
    unsigned int x = v.i;
    unsigned int r = (x + 0x7FFFu + ((x >> 16) & 1u)) >> 16;
    return (unsigned short)r;
}
// packed fp32x2 -> bf16x2 (RNE)
__device__ __forceinline__ unsigned int pk2(float a, float b) {
    __hip_bfloat162 t = __float22bfloat162_rn(make_float2(a, b));
    union { __hip_bfloat162 v; unsigned int u; } c; c.v = t; return c.u;
}
// 8 consecutive fp32 -> bf16 fragment (used by rec for W_hh, once per block)
__device__ __forceinline__ s16x8 cvt8v(const float* p) {
    f32x4 a = *(const f32x4*)p;
    f32x4 b = *(const f32x4*)(p + 4);
    s16x8 r;
    r[0] = (short)f2b(a[0]); r[1] = (short)f2b(a[1]);
    r[2] = (short)f2b(a[2]); r[3] = (short)f2b(a[3]);
    r[4] = (short)f2b(b[0]); r[5] = (short)f2b(b[1]);
    r[6] = (short)f2b(b[2]); r[7] = (short)f2b(b[3]);
    return r;
}
__device__ __forceinline__ float sigm(float x) {
    return __builtin_amdgcn_rcpf(1.f + __expf(-x));
}
__device__ __forceinline__ float tanh_f(float x) {
    return 1.f - 2.f * __builtin_amdgcn_rcpf(1.f + __expf(2.f * x));
}
__device__ __forceinline__ void gload16(const void* gsrc, void* lds) {
    __builtin_amdgcn_global_load_lds(
        (const __attribute__((address_space(1))) unsigned int*)gsrc,
        (__attribute__((address_space(3))) unsigned int*)lds, 16, 0, 0);
}
// LDS-only barrier: waits DS ops but NOT outstanding global loads/stores.
// Safe when inter-wave communication is exclusively through LDS.
__device__ __forceinline__ void ldsbar() {
    asm volatile("s_waitcnt lgkmcnt(0)\n\ts_barrier" ::: "memory");
}

// ---------------------------------------------------------------------------
// prep: fp32 -> bf16 conversions into d_out scratch (y1 region, written last)
// ---------------------------------------------------------------------------
__global__ __launch_bounds__(256)
void prep(const float* __restrict__ x,
          const float* __restrict__ w0f, const float* __restrict__ w0b,
          const float* __restrict__ w1f, const float* __restrict__ w1b,
          unsigned short* __restrict__ xb,
          unsigned short* __restrict__ w0bf,
          unsigned short* __restrict__ w1bf)
{
    int tid = blockIdx.x * 256 + threadIdx.x;
    int nthr = gridDim.x * 256;
    for (int idx = tid; idx < Mn * 32; idx += nthr) {
        int row = idx >> 5, col = idx & 31;
        xb[idx] = f2b(col < 24 ? x[row * 24 + col] : 0.f);
    }
    for (int idx = tid; idx < 2 * 512 * 32; idx += nthr) {
        int d = idx >> 14, rem = idx & 16383;
        int n = rem >> 5, col = rem & 31;
        const float* w = d ? w0b : w0f;
        w0bf[idx] = f2b(col < 24 ? w[n * 24 + col] : 0.f);
    }
    for (int idx = tid; idx < 2 * 512 * 256; idx += nthr) {
        int d = idx >> 17, rem = idx & 131071;
        const float* w = d ? w1b : w1f;
        w1bf[idx] = f2b(w[rem]);
    }
}

// ---------------------------------------------------------------------------
// Tiled GEMM (unchanged, passing): gx[dir][m][n] = A@W^T, bf16.
// ---------------------------------------------------------------------------
template<int BK, int KOUT>
__global__ __launch_bounds__(256, 2)
void gemm_tile(const unsigned short* __restrict__ A, int lda,
               const unsigned short* __restrict__ W,   // [2][512][BK*KOUT]
               unsigned short* __restrict__ gx)
{
    constexpr int GR = BK / 8;
    constexpr int SWM = (GR >= 8) ? 7 : (GR - 1);
    constexpr int ASZ = 128 * BK * 2;
    constexpr int GOFF = (BK == 128) ? 0 : 2 * ASZ;
    constexpr int SMEM = 2 * ASZ + ((BK == 128) ? 0 : 4 * 16 * 68 * 4);
    __shared__ char smem[SMEM];
    unsigned short* Atile = (unsigned short*)smem;
    unsigned short* Btile = (unsigned short*)(smem + ASZ);

    const int K = BK * KOUT;
    const int mb = blockIdx.x;
    const int nb = blockIdx.y;
    const int dir = nb >> 2, ncol0 = (nb & 3) * 128;
    const int row0 = mb * 128;
    const unsigned short* Asrc = A + (size_t)row0 * lda;
    const unsigned short* Bsrc = W + (size_t)dir * 512 * K + (size_t)ncol0 * K;
    unsigned short* out = gx + (size_t)dir * Mn * G4;

    const int tid = threadIdx.x;
    const int w = tid >> 6, l = tid & 63;
    const int q = l >> 4, i = l & 15;
    const int wm = w >> 1, wn = w & 1;

    f32x4 acc[4][4];
#pragma unroll
    for (int a = 0; a < 4; ++a)
#pragma unroll
        for (int b = 0; b < 4; ++b) acc[a][b] = f32x4{0.f, 0.f, 0.f, 0.f};

    for (int ko = 0; ko < KOUT; ++ko) {
#pragma unroll
        for (int it = 0; it < (128 * GR) / 256; ++it) {
            int g = it * 256 + tid;
            int row = g / GR, p = g % GR;
            int gi = p ^ (row & SWM);
            gload16(Asrc + (size_t)row * lda + ko * BK + gi * 8,
                    (char*)Atile + g * 16);
        }
#pragma unroll
        for (int it = 0; it < (128 * GR) / 256; ++it) {
            int g = it * 256 + tid;
            int row = g / GR, p = g % GR;
            int gi = p ^ (row & SWM);
            gload16(Bsrc + (size_t)row * K + ko * BK + gi * 8,
                    (char*)Btile + g * 16);
        }
        __syncthreads();   // must drain vmcnt (global_load_lds) — keep full sync
#pragma unroll
        for (int kf = 0; kf < BK / 32; ++kf) {
            s16x8 af[4], bf[4];
#pragma unroll
            for (int mt = 0; mt < 4; ++mt) {
                int ar = wm * 64 + mt * 16 + i;
                int p = (kf * 4 + q) ^ (ar & SWM);
                af[mt] = *(const s16x8*)((char*)Atile + (ar * GR + p) * 16);
            }
#pragma unroll
            for (int nt = 0; nt < 4; ++nt) {
                int br = wn * 64 + nt * 16 + i;
                int p = (kf * 4 + q) ^ (br & SWM);
                bf[nt] = *(const s16x8*)((char*)Btile + (br * GR + p) * 16);
            }
#pragma unroll
            for (int mt = 0; mt < 4; ++mt)
#pragma unroll
                for (int nt = 0; nt < 4; ++nt)
                    acc[mt][nt] = __builtin_amdgcn_mfma_f32_16x16x32_bf16(
                        af[mt], bf[nt], acc[mt][nt], 0, 0, 0);
        }
        __syncthreads();
    }

    float* gbufw = (float*)(smem + GOFF) + w * (16 * 68);
#pragma unroll
    for (int mt = 0; mt < 4; ++mt) {
#pragma unroll
        for (int nt = 0; nt < 4; ++nt)
#pragma unroll
            for (int r = 0; r < 4; ++r)
                gbufw[(q * 4 + r) * 68 + nt * 16 + i] = acc[mt][nt][r];
        __syncthreads();
#pragma unroll
        for (int it2 = 0; it2 < 2; ++it2) {
            int rr = (l >> 3) + it2 * 8;
            int cc = (l & 7) * 8;
            const float* gsrc = gbufw + rr * 68 + cc;
            uint4 pv;
            pv.x = pk2(gsrc[0], gsrc[1]);
            pv.y = pk2(gsrc[2], gsrc[3]);
            pv.z = pk2(gsrc[4], gsrc[5]);
            pv.w = pk2(gsrc[6], gsrc[7]);
            *(uint4*)(out + (size_t)(row0 + wm * 64 + mt * 16 + rr) * G4
                          + ncol0 + wn * 64 + cc) = pv;
        }
        __syncthreads();
    }
}

// ---------------------------------------------------------------------------
// Recurrent sweep v5: TWO independent same-dir chains per block.
//
// Evidence (r1/r2): per-step time (~1900 cyc) is a fixed latency skeleton,
// insensitive to barriers / bank conflicts / VALU count. Fix: fill the
// skeleton with a second independent recurrence. Block owns 2 batch-pairs
// (same dir -> W_hh fragments shared, ~300 VGPR total). Per step: 8
// ds_reads, 64 MFMA/wave (16 indep chains per kf-group), 2 elementwise
// chains/lane, ONE shared barrier. Chain alpha's latency overlaps chain
// beta's compute and vice versa.
//
// Per-chain mapping (unchanged from v4, which passed):
//   wave w, lane (q,i); u=q&1, r=q>>1; j=32w+16u+i; batch = base + r.
//   A-replication row p = h[batch p>>3]; C element 0 at lane (q,i) is
//   (batch q>>1, n-tile col i) -> all 4 gates in-lane via 1 cndmask each.
// Unroll reduced 8->4 (prefetch depth 4, ~6000 cyc ahead, >> HBM ~900) to
// keep the doubled body inside 32 KiB L1I.
// ---------------------------------------------------------------------------
template<int LAYER>
__global__ __launch_bounds__(256, 1)
void lstm_rec(const unsigned short* __restrict__ gx,
              const float* __restrict__ Whf,
              const float* __restrict__ Whb,
              const float* __restrict__ biasf,
              const float* __restrict__ biasb,
              float* __restrict__ y,
              unsigned short* __restrict__ y0b,
              float* __restrict__ hn,
              float* __restrict__ cn)
{
    const int pb  = blockIdx.x;          // 0..63 : owns batches 4*pb..4*pb+3
    const int dir = blockIdx.y;
    const float* Wh   = dir ? Whb : Whf;
    const float* bias = dir ? biasb : biasf;
    const unsigned short* gxd = gx + (size_t)dir * Mn * G4;

    const int tid = threadIdx.x;
    const int w = tid >> 6;          // wave 0..3
    const int l = tid & 63;
    const int q = l >> 4, i = l & 15;
    const int u = q & 1;             // j-subtile select
    const int r = q >> 1;            // batch-in-pair select
    const int j = 32 * w + 16 * u + i;
    const int b0 = pb * 4;

    __shared__ __align__(16) unsigned short hbuf[4][160];   // 2 chains x 2 rows

    for (int idx = tid; idx < 4 * 160; idx += 256)
        ((unsigned short*)hbuf)[idx] = 0;

    // W_hh fragments (SHARED by both chains): tile (g,u): n=128g+32w+16ut+i
    s16x8 wh[4][2][4];
#pragma unroll
    for (int g = 0; g < 4; ++g)
#pragma unroll
        for (int ut = 0; ut < 2; ++ut) {
            int n = 128 * g + 32 * w + 16 * ut + i;
#pragma unroll
            for (int kf = 0; kf < 4; ++kf)
                wh[g][ut][kf] = cvt8v(Wh + (size_t)n * Hn + kf * 32 + q * 8);
        }

    const float bi = bias[j],       bfv = bias[128 + j];
    const float bg = bias[256 + j], bo  = bias[384 + j];
    float cc[2] = {0.f, 0.f}, hl[2] = {0.f, 0.f};

    // hoisted LDS pointers per chain (A row p -> h[batch p>>3])
    const s16x8* ahp[2][4];
    unsigned short* hw[2];
#pragma unroll
    for (int ch = 0; ch < 2; ++ch) {
#pragma unroll
        for (int kf = 0; kf < 4; ++kf)
            ahp[ch][kf] = (const s16x8*)&hbuf[2 * ch + (i >> 3)][kf * 32 + q * 8];
        hw[ch] = &hbuf[2 * ch + r][j];
    }

    // strength-reduced global pointers per chain
    const intptr_t gstep = dir ? -(intptr_t)G4 : (intptr_t)G4;
    const intptr_t ystep = dir ? (intptr_t)-256 : (intptr_t)256;
    const int t0 = dir ? Tn - 1 : 0;
    const unsigned short* p0c[2];
    const unsigned short* gp_pre[2];
    float* ypp[2];
    unsigned short* y0pp[2];
#pragma unroll
    for (int ch = 0; ch < 2; ++ch) {
        const int b = b0 + 2 * ch + r;
        p0c[ch]   = gxd + ((size_t)b * Tn + t0) * G4 + j;
        gp_pre[ch] = p0c[ch] + 4 * gstep;           // addr of logical step 4
        ypp[ch]   = y  + ((size_t)b * Tn + t0) * 256 + dir * 128 + j;
        y0pp[ch]  = y0b + ((size_t)b * Tn + t0) * 256 + dir * 128 + j;
    }

    // gx prefetch double-buffer, depth 4: raw bf16 bits, converted at use.
    unsigned short bufA[2][4][4], bufB[2][4][4];
#pragma unroll
    for (int ch = 0; ch < 2; ++ch)
#pragma unroll
        for (int f = 0; f < 4; ++f) {
            const unsigned short* gp = p0c[ch] + f * gstep;
            bufA[ch][0][f] = gp[0];
            bufA[ch][1][f] = gp[128];
            bufA[ch][2][f] = gp[256];
            bufA[ch][3][f] = gp[384];
        }

    __syncthreads();   // once: covers hbuf zero-init

    auto do4 = [&](unsigned short (&useB)[2][4][4],
                   unsigned short (&ldB)[2][4][4], int sb) {
#pragma unroll
        for (int f = 0; f < 4; ++f) {
            const int s = sb + f;

            // latency head: issue all 8 LDS h reads
            s16x8 ah[2][4];
#pragma unroll
            for (int ch = 0; ch < 2; ++ch)
#pragma unroll
                for (int kf = 0; kf < 4; ++kf)
                    ah[ch][kf] = *ahp[ch][kf];

            // prefetch gx for step s+4 (both chains)
#pragma unroll
            for (int ch = 0; ch < 2; ++ch) {
                ldB[ch][0][f] = gp_pre[ch][0];
                ldB[ch][1][f] = gp_pre[ch][128];
                ldB[ch][2][f] = gp_pre[ch][256];
                ldB[ch][3][f] = gp_pre[ch][384];
            }
            if (s < Tn - 5) { gp_pre[0] += gstep; gp_pre[1] += gstep; }

            // pre-combine gx + bias (registers only)
            float pc[2][4];
#pragma unroll
            for (int ch = 0; ch < 2; ++ch) {
                pc[ch][0] = b2f(useB[ch][0][f]) + bi;
                pc[ch][1] = b2f(useB[ch][1][f]) + bfv;
                pc[ch][2] = b2f(useB[ch][2][f]) + bg;
                pc[ch][3] = b2f(useB[ch][3][f]) + bo;
            }

            f32x4 acc[2][4][2];
#pragma unroll
            for (int ch = 0; ch < 2; ++ch)
#pragma unroll
                for (int g = 0; g < 4; ++g)
#pragma unroll
                    for (int ut = 0; ut < 2; ++ut)
                        acc[ch][g][ut] = f32x4{0.f, 0.f, 0.f, 0.f};
            // kf-outer: 16 independent accumulator chains per kf group
#pragma unroll
            for (int kf = 0; kf < 4; ++kf)
#pragma unroll
                for (int ch = 0; ch < 2; ++ch)
#pragma unroll
                    for (int g = 0; g < 4; ++g)
#pragma unroll
                        for (int ut = 0; ut < 2; ++ut)
                            acc[ch][g][ut] =
                                __builtin_amdgcn_mfma_f32_16x16x32_bf16(
                                    ah[ch][kf], wh[g][ut][kf],
                                    acc[ch][g][ut], 0, 0, 0);

            // readout + elementwise, both chains (independent -> ILP)
#pragma unroll
            for (int ch = 0; ch < 2; ++ch) {
                const float s_i = u ? acc[ch][0][1][0] : acc[ch][0][0][0];
                const float s_f = u ? acc[ch][1][1][0] : acc[ch][1][0][0];
                const float s_g = u ? acc[ch][2][1][0] : acc[ch][2][0][0];
                const float s_o = u ? acc[ch][3][1][0] : acc[ch][3][0][0];

                float g_i = s_i + pc[ch][0];
                float g_f = s_f + pc[ch][1];
                float g_g = s_g + pc[ch][2];
                float g_o = s_o + pc[ch][3];
                float iv = sigm(g_i), fv = sigm(g_f), ov = sigm(g_o);
                float gv = tanh_f(g_g);
                cc[ch] = fv * cc[ch] + iv * gv;
                float h = ov * tanh_f(cc[ch]);
                hl[ch] = h;
                unsigned int hp;
                asm("v_cvt_pk_bf16_f32 %0, %1, %2" : "=v"(hp) : "v"(h), "v"(h));
                unsigned short hb = (unsigned short)hp;
                *hw[ch] = hb;
                if (LAYER == 0) *y0pp[ch] = hb;     // fire-and-forget
                else            *ypp[ch]  = h;
                ypp[ch] += ystep; y0pp[ch] += ystep;
            }

            ldsbar();   // single barrier: hbuf writes -> next step's A reads
        }
    };

    for (int sb = 0; sb < Tn; sb += 8) {
        do4(bufA, bufB, sb);
        do4(bufB, bufA, sb + 4);
    }

    const int slot = LAYER * 2 + dir;
#pragma unroll
    for (int ch = 0; ch < 2; ++ch) {
        const int b = b0 + 2 * ch + r;
        hn[((size_t)slot * Bn + b) * Hn + j] = hl[ch];
        cn[((size_t)slot * Bn + b) * Hn + j] = cc[ch];
    }
}

// ---------------------------------------------------------------------------
extern "C" void kernel_launch(void* const* d_in, const int* in_sizes, int n_in,
                              void* d_out, int out_size, void* d_ws, size_t ws_size,
                              hipStream_t stream)
{
    const float* x     = (const float*)d_in[0];
    const float* wih0f = (const float*)d_in[1];
    const float* whh0f = (const float*)d_in[2];
    const float* b0f   = (const float*)d_in[3];
    const float* wih0b = (const float*)d_in[4];
    const float* whh0b = (const float*)d_in[5];
    const float* b0b   = (const float*)d_in[6];
    const float* wih1f = (const float*)d_in[7];
    const float* whh1f = (const float*)d_in[8];
    const float* b1f   = (const float*)d_in[9];
    const float* wih1b = (const float*)d_in[10];
    const float* whh1b = (const float*)d_in[11];
    const float* b1b   = (const float*)d_in[12];

    float* y  = (float*)d_out;                       // [B][T][256] fp32 (final)
    float* hn = y + (size_t)Mn * 256;                // [4][B][128]
    float* cn = hn + (size_t)4 * Bn * Hn;            // [4][B][128]
    unsigned short* gx = (unsigned short*)d_ws;      // [2][M][512] bf16 = 256 MiB

    unsigned short* scr  = (unsigned short*)d_out;
    unsigned short* y0b  = scr;                              // [M][256] bf16
    unsigned short* xb   = scr + (size_t)Mn * 256;           // [M][32]
    unsigned short* w0bf = xb  + (size_t)Mn * 32;            // [2][512][32]
    unsigned short* w1bf = w0bf + 2 * 512 * 32;              // [2][512][256]

    prep<<<2048, 256, 0, stream>>>(x, wih0f, wih0b, wih1f, wih1b, xb, w0bf, w1bf);

    dim3 gg(1024, 8), gb(256);
    dim3 rg(64, 2), rb(256);

    gemm_tile<32, 1><<<gg, gb, 0, stream>>>(xb, 32, w0bf, gx);
    lstm_rec<0><<<rg, rb, 0, stream>>>(gx, whh0f, whh0b, b0f, b0b, y, y0b, hn, cn);
    gemm_tile<128, 2><<<gg, gb, 0, stream>>>(y0b, 256, w1bf, gx);
    lstm_rec<1><<<rg, rb, 0, stream>>>(gx, whh1f, whh1b, b1f, b1b, y, y0b, hn, cn);
}

// Round 4
// 1174.391 us; speedup vs baseline: 1.0119x; 1.0119x over previous
//
#include <hip/hip_runtime.h>
#include <hip/hip_bf16.h>
#include <stdint.h>

#define Bn 256
#define Tn 512
#define Hn 128
#define G4 512   // 4*H
#define Mn (Bn*Tn)

typedef __attribute__((ext_vector_type(8))) short s16x8;
typedef __attribute__((ext_vector_type(4))) float f32x4;

__device__ __forceinline__ float b2f(unsigned short u) {
    union { unsigned int i; float f; } v; v.i = ((unsigned int)u) << 16; return v.f;
}
__device__ __forceinline__ unsigned short f2b(float f) {
    union { float f; unsigned int i; } v; v.f = f;
    unsigned int x = v.i;
    unsigned int r = (x + 0x7FFFu + ((x >> 16) & 1u)) >> 16;
    return (unsigned short)r;
}
// packed fp32x2 -> bf16x2 (RNE)
__device__ __forceinline__ unsigned int pk2(float a, float b) {
    __hip_bfloat162 t = __float22bfloat162_rn(make_float2(a, b));
    union { __hip_bfloat162 v; unsigned int u; } c; c.v = t; return c.u;
}
// 8 consecutive fp32 -> bf16 fragment (used by rec for W_hh, once per block)
__device__ __forceinline__ s16x8 cvt8v(const float* p) {
    f32x4 a = *(const f32x4*)p;
    f32x4 b = *(const f32x4*)(p + 4);
    s16x8 r;
    r[0] = (short)f2b(a[0]); r[1] = (short)f2b(a[1]);
    r[2] = (short)f2b(a[2]); r[3] = (short)f2b(a[3]);
    r[4] = (short)f2b(b[0]); r[5] = (short)f2b(b[1]);
    r[6] = (short)f2b(b[2]); r[7] = (short)f2b(b[3]);
    return r;
}
__device__ __forceinline__ float sigm(float x) {
    return __builtin_amdgcn_rcpf(1.f + __expf(-x));
}
__device__ __forceinline__ float tanh_f(float x) {
    return 1.f - 2.f * __builtin_amdgcn_rcpf(1.f + __expf(2.f * x));
}
__device__ __forceinline__ void gload16(const void* gsrc, void* lds) {
    __builtin_amdgcn_global_load_lds(
        (const __attribute__((address_space(1))) unsigned int*)gsrc,
        (__attribute__((address_space(3))) unsigned int*)lds, 16, 0, 0);
}
// LDS-only barrier: waits DS ops but NOT outstanding global loads/stores.
// Safe when inter-wave communication is exclusively through LDS.
__device__ __forceinline__ void ldsbar() {
    asm volatile("s_waitcnt lgkmcnt(0)\n\ts_barrier" ::: "memory");
}

// ---------------------------------------------------------------------------
// prep: fp32 -> bf16 conversions into d_out scratch (y1 region, written last)
// ---------------------------------------------------------------------------
__global__ __launch_bounds__(256)
void prep(const float* __restrict__ x,
          const float* __restrict__ w0f, const float* __restrict__ w0b,
          const float* __restrict__ w1f, const float* __restrict__ w1b,
          unsigned short* __restrict__ xb,
          unsigned short* __restrict__ w0bf,
          unsigned short* __restrict__ w1bf)
{
    int tid = blockIdx.x * 256 + threadIdx.x;
    int nthr = gridDim.x * 256;
    for (int idx = tid; idx < Mn * 32; idx += nthr) {
        int row = idx >> 5, col = idx & 31;
        xb[idx] = f2b(col < 24 ? x[row * 24 + col] : 0.f);
    }
    for (int idx = tid; idx < 2 * 512 * 32; idx += nthr) {
        int d = idx >> 14, rem = idx & 16383;
        int n = rem >> 5, col = rem & 31;
        const float* w = d ? w0b : w0f;
        w0bf[idx] = f2b(col < 24 ? w[n * 24 + col] : 0.f);
    }
    for (int idx = tid; idx < 2 * 512 * 256; idx += nthr) {
        int d = idx >> 17, rem = idx & 131071;
        const float* w = d ? w1b : w1f;
        w1bf[idx] = f2b(w[rem]);
    }
}

// ---------------------------------------------------------------------------
// Tiled GEMM (unchanged, passing): gx[dir][m][n] = A@W^T, bf16.
// ---------------------------------------------------------------------------
template<int BK, int KOUT>
__global__ __launch_bounds__(256, 2)
void gemm_tile(const unsigned short* __restrict__ A, int lda,
               const unsigned short* __restrict__ W,   // [2][512][BK*KOUT]
               unsigned short* __restrict__ gx)
{
    constexpr int GR = BK / 8;
    constexpr int SWM = (GR >= 8) ? 7 : (GR - 1);
    constexpr int ASZ = 128 * BK * 2;
    constexpr int GOFF = (BK == 128) ? 0 : 2 * ASZ;
    constexpr int SMEM = 2 * ASZ + ((BK == 128) ? 0 : 4 * 16 * 68 * 4);
    __shared__ char smem[SMEM];
    unsigned short* Atile = (unsigned short*)smem;
    unsigned short* Btile = (unsigned short*)(smem + ASZ);

    const int K = BK * KOUT;
    const int mb = blockIdx.x;
    const int nb = blockIdx.y;
    const int dir = nb >> 2, ncol0 = (nb & 3) * 128;
    const int row0 = mb * 128;
    const unsigned short* Asrc = A + (size_t)row0 * lda;
    const unsigned short* Bsrc = W + (size_t)dir * 512 * K + (size_t)ncol0 * K;
    unsigned short* out = gx + (size_t)dir * Mn * G4;

    const int tid = threadIdx.x;
    const int w = tid >> 6, l = tid & 63;
    const int q = l >> 4, i = l & 15;
    const int wm = w >> 1, wn = w & 1;

    f32x4 acc[4][4];
#pragma unroll
    for (int a = 0; a < 4; ++a)
#pragma unroll
        for (int b = 0; b < 4; ++b) acc[a][b] = f32x4{0.f, 0.f, 0.f, 0.f};

    for (int ko = 0; ko < KOUT; ++ko) {
#pragma unroll
        for (int it = 0; it < (128 * GR) / 256; ++it) {
            int g = it * 256 + tid;
            int row = g / GR, p = g % GR;
            int gi = p ^ (row & SWM);
            gload16(Asrc + (size_t)row * lda + ko * BK + gi * 8,
                    (char*)Atile + g * 16);
        }
#pragma unroll
        for (int it = 0; it < (128 * GR) / 256; ++it) {
            int g = it * 256 + tid;
            int row = g / GR, p = g % GR;
            int gi = p ^ (row & SWM);
            gload16(Bsrc + (size_t)row * K + ko * BK + gi * 8,
                    (char*)Btile + g * 16);
        }
        __syncthreads();   // must drain vmcnt (global_load_lds) — keep full sync
#pragma unroll
        for (int kf = 0; kf < BK / 32; ++kf) {
            s16x8 af[4], bf[4];
#pragma unroll
            for (int mt = 0; mt < 4; ++mt) {
                int ar = wm * 64 + mt * 16 + i;
                int p = (kf * 4 + q) ^ (ar & SWM);
                af[mt] = *(const s16x8*)((char*)Atile + (ar * GR + p) * 16);
            }
#pragma unroll
            for (int nt = 0; nt < 4; ++nt) {
                int br = wn * 64 + nt * 16 + i;
                int p = (kf * 4 + q) ^ (br & SWM);
                bf[nt] = *(const s16x8*)((char*)Btile + (br * GR + p) * 16);
            }
#pragma unroll
            for (int mt = 0; mt < 4; ++mt)
#pragma unroll
                for (int nt = 0; nt < 4; ++nt)
                    acc[mt][nt] = __builtin_amdgcn_mfma_f32_16x16x32_bf16(
                        af[mt], bf[nt], acc[mt][nt], 0, 0, 0);
        }
        __syncthreads();
    }

    float* gbufw = (float*)(smem + GOFF) + w * (16 * 68);
#pragma unroll
    for (int mt = 0; mt < 4; ++mt) {
#pragma unroll
        for (int nt = 0; nt < 4; ++nt)
#pragma unroll
            for (int r = 0; r < 4; ++r)
                gbufw[(q * 4 + r) * 68 + nt * 16 + i] = acc[mt][nt][r];
        __syncthreads();
#pragma unroll
        for (int it2 = 0; it2 < 2; ++it2) {
            int rr = (l >> 3) + it2 * 8;
            int cc = (l & 7) * 8;
            const float* gsrc = gbufw + rr * 68 + cc;
            uint4 pv;
            pv.x = pk2(gsrc[0], gsrc[1]);
            pv.y = pk2(gsrc[2], gsrc[3]);
            pv.z = pk2(gsrc[4], gsrc[5]);
            pv.w = pk2(gsrc[6], gsrc[7]);
            *(uint4*)(out + (size_t)(row0 + wm * 64 + mt * 16 + rr) * G4
                          + ncol0 + wn * 64 + cc) = pv;
        }
        __syncthreads();
    }
}

// ---------------------------------------------------------------------------
// Recurrent sweep v6: ONE batch per block, 512 blocks -> 2 blocks/CU.
//
// Evidence (r1-r3): per-step time ~1900 cyc is ~85% exposed latency (v5:
// adding a whole second chain in-wave cost only +258 cyc). All prior
// versions ran 256 blocks = 1 wave/SIMD: zero TLP, every stall exposed.
// Fix: halve the per-block batch count and double the grid. Two
// co-resident blocks per CU = 2 waves/SIMD with INDEPENDENT barriers
// (independent phases) -> each wave's stalls are filled by the other's
// issue. MFMA count/wave unchanged (M-dim replication waste doubles device
// MFMA ops; MFMA issue is only ~160cyc of the step - cheap to pay).
//
// Mapping (from v4, passing): wave w, lane (q,i); u=q&1; j=32w+16u+i.
// A rows all = h[batch] (broadcast read), so C element 0 at every lane is
// (batch, col i) -> gate g of j in-lane via 1 cndmask. Lanes q / q+2
// duplicate work (harmless; identical values to identical addresses).
// kf-split accumulators (2 chains of depth 2) shorten the MFMA dep tail.
// VGPR must stay <= 256 for 2 waves/SIMD.
// ---------------------------------------------------------------------------
template<int LAYER>
__global__ __launch_bounds__(256, 2)
void lstm_rec(const unsigned short* __restrict__ gx,
              const float* __restrict__ Whf,
              const float* __restrict__ Whb,
              const float* __restrict__ biasf,
              const float* __restrict__ biasb,
              float* __restrict__ y,
              unsigned short* __restrict__ y0b,
              float* __restrict__ hn,
              float* __restrict__ cn)
{
    const int b   = blockIdx.x;          // one batch per block
    const int dir = blockIdx.y;
    const float* Wh   = dir ? Whb : Whf;
    const float* bias = dir ? biasb : biasf;
    const unsigned short* gxd = gx + (size_t)dir * Mn * G4;

    const int tid = threadIdx.x;
    const int w = tid >> 6;          // wave 0..3
    const int l = tid & 63;
    const int q = l >> 4, i = l & 15;
    const int u = q & 1;             // j-subtile select
    const int j = 32 * w + 16 * u + i;

    __shared__ __align__(16) unsigned short hbuf[160];   // one h row, 320B

    for (int idx = tid; idx < 160; idx += 256)
        hbuf[idx] = 0;

    // W_hh fragments: tile (g,ut): n = 128g + 32w + 16ut + i (B col = i)
    s16x8 wh[4][2][4];
#pragma unroll
    for (int g = 0; g < 4; ++g)
#pragma unroll
        for (int ut = 0; ut < 2; ++ut) {
            int n = 128 * g + 32 * w + 16 * ut + i;
#pragma unroll
            for (int kf = 0; kf < 4; ++kf)
                wh[g][ut][kf] = cvt8v(Wh + (size_t)n * Hn + kf * 32 + q * 8);
        }

    const float bi = bias[j],       bfv = bias[128 + j];
    const float bg = bias[256 + j], bo  = bias[384 + j];
    float c = 0.f, hlast = 0.f;

    // hoisted LDS pointers: every A row = h[batch] (wave-broadcast reads)
    const s16x8* ah0p = (const s16x8*)&hbuf[0 * 32 + q * 8];
    const s16x8* ah1p = (const s16x8*)&hbuf[1 * 32 + q * 8];
    const s16x8* ah2p = (const s16x8*)&hbuf[2 * 32 + q * 8];
    const s16x8* ah3p = (const s16x8*)&hbuf[3 * 32 + q * 8];
    unsigned short* hw = &hbuf[j];

    // strength-reduced global pointers
    const intptr_t gstep = dir ? -(intptr_t)G4 : (intptr_t)G4;
    const intptr_t ystep = dir ? (intptr_t)-256 : (intptr_t)256;
    const int t0 = dir ? Tn - 1 : 0;
    const unsigned short* p0 = gxd + ((size_t)b * Tn + t0) * G4 + j;
    const unsigned short* gp_pre = p0 + 4 * gstep;   // addr of logical step 4
    float* yp = y + ((size_t)b * Tn + t0) * 256 + dir * 128 + j;
    unsigned short* y0p = y0b + ((size_t)b * Tn + t0) * 256 + dir * 128 + j;

    // gx prefetch double-buffer, depth 4: raw bf16 bits, converted at use.
    unsigned short bufA[4][4], bufB[4][4];
#pragma unroll
    for (int f = 0; f < 4; ++f) {
        const unsigned short* gp = p0 + f * gstep;
        bufA[0][f] = gp[0];
        bufA[1][f] = gp[128];
        bufA[2][f] = gp[256];
        bufA[3][f] = gp[384];
    }

    __syncthreads();   // once: covers hbuf zero-init

    auto do4 = [&](unsigned short (&useB)[4][4], unsigned short (&ldB)[4][4],
                   int sb) {
#pragma unroll
        for (int f = 0; f < 4; ++f) {
            const int s = sb + f;

            // latency head: issue the 4 LDS h reads (wave-broadcast)
            s16x8 ah0 = *ah0p, ah1 = *ah1p, ah2 = *ah2p, ah3 = *ah3p;

            // prefetch gx for step s+4
            ldB[0][f] = gp_pre[0];
            ldB[1][f] = gp_pre[128];
            ldB[2][f] = gp_pre[256];
            ldB[3][f] = gp_pre[384];
            if (s < Tn - 5) gp_pre += gstep;

            // pre-combine gx + bias (registers only)
            const float pi = b2f(useB[0][f]) + bi;
            const float pf = b2f(useB[1][f]) + bfv;
            const float pg = b2f(useB[2][f]) + bg;
            const float po = b2f(useB[3][f]) + bo;

            // kf-split accumulators: two dep chains of depth 2 per tile
            f32x4 a0[4][2], a1[4][2];
#pragma unroll
            for (int g = 0; g < 4; ++g)
#pragma unroll
                for (int ut = 0; ut < 2; ++ut) {
                    a0[g][ut] = f32x4{0.f, 0.f, 0.f, 0.f};
                    a1[g][ut] = f32x4{0.f, 0.f, 0.f, 0.f};
                }
#pragma unroll
            for (int g = 0; g < 4; ++g)
#pragma unroll
                for (int ut = 0; ut < 2; ++ut)
                    a0[g][ut] = __builtin_amdgcn_mfma_f32_16x16x32_bf16(
                        ah0, wh[g][ut][0], a0[g][ut], 0, 0, 0);
#pragma unroll
            for (int g = 0; g < 4; ++g)
#pragma unroll
                for (int ut = 0; ut < 2; ++ut)
                    a1[g][ut] = __builtin_amdgcn_mfma_f32_16x16x32_bf16(
                        ah1, wh[g][ut][1], a1[g][ut], 0, 0, 0);
#pragma unroll
            for (int g = 0; g < 4; ++g)
#pragma unroll
                for (int ut = 0; ut < 2; ++ut)
                    a0[g][ut] = __builtin_amdgcn_mfma_f32_16x16x32_bf16(
                        ah2, wh[g][ut][2], a0[g][ut], 0, 0, 0);
#pragma unroll
            for (int g = 0; g < 4; ++g)
#pragma unroll
                for (int ut = 0; ut < 2; ++ut)
                    a1[g][ut] = __builtin_amdgcn_mfma_f32_16x16x32_bf16(
                        ah3, wh[g][ut][3], a1[g][ut], 0, 0, 0);

            // in-lane gate select (element 0; all C rows identical) + join
            const float s_i = (u ? a0[0][1][0] : a0[0][0][0])
                            + (u ? a1[0][1][0] : a1[0][0][0]);
            const float s_f = (u ? a0[1][1][0] : a0[1][0][0])
                            + (u ? a1[1][1][0] : a1[1][0][0]);
            const float s_g = (u ? a0[2][1][0] : a0[2][0][0])
                            + (u ? a1[2][1][0] : a1[2][0][0]);
            const float s_o = (u ? a0[3][1][0] : a0[3][0][0])
                            + (u ? a1[3][1][0] : a1[3][0][0]);

            float g_i = s_i + pi;
            float g_f = s_f + pf;
            float g_g = s_g + pg;
            float g_o = s_o + po;
            float iv = sigm(g_i), fv = sigm(g_f), ov = sigm(g_o);
            float gv = tanh_f(g_g);
            c = fv * c + iv * gv;
            float h = ov * tanh_f(c);
            hlast = h;
            unsigned int hp;
            asm("v_cvt_pk_bf16_f32 %0, %1, %2" : "=v"(hp) : "v"(h), "v"(h));
            unsigned short hb = (unsigned short)hp;
            *hw = hb;                               // dup lanes: same value/addr
            if (LAYER == 0) *y0p = hb;              // fire-and-forget
            else            *yp  = h;
            yp += ystep; y0p += ystep;

            ldsbar();   // single barrier: hbuf write -> next step's A read
        }
    };

    for (int sb = 0; sb < Tn; sb += 8) {
        do4(bufA, bufB, sb);
        do4(bufB, bufA, sb + 4);
    }

    const int slot = LAYER * 2 + dir;
    hn[((size_t)slot * Bn + b) * Hn + j] = hlast;
    cn[((size_t)slot * Bn + b) * Hn + j] = c;
}

// ---------------------------------------------------------------------------
extern "C" void kernel_launch(void* const* d_in, const int* in_sizes, int n_in,
                              void* d_out, int out_size, void* d_ws, size_t ws_size,
                              hipStream_t stream)
{
    const float* x     = (const float*)d_in[0];
    const float* wih0f = (const float*)d_in[1];
    const float* whh0f = (const float*)d_in[2];
    const float* b0f   = (const float*)d_in[3];
    const float* wih0b = (const float*)d_in[4];
    const float* whh0b = (const float*)d_in[5];
    const float* b0b   = (const float*)d_in[6];
    const float* wih1f = (const float*)d_in[7];
    const float* whh1f = (const float*)d_in[8];
    const float* b1f   = (const float*)d_in[9];
    const float* wih1b = (const float*)d_in[10];
    const float* whh1b = (const float*)d_in[11];
    const float* b1b   = (const float*)d_in[12];

    float* y  = (float*)d_out;                       // [B][T][256] fp32 (final)
    float* hn = y + (size_t)Mn * 256;                // [4][B][128]
    float* cn = hn + (size_t)4 * Bn * Hn;            // [4][B][128]
    unsigned short* gx = (unsigned short*)d_ws;      // [2][M][512] bf16 = 256 MiB

    unsigned short* scr  = (unsigned short*)d_out;
    unsigned short* y0b  = scr;                              // [M][256] bf16
    unsigned short* xb   = scr + (size_t)Mn * 256;           // [M][32]
    unsigned short* w0bf = xb  + (size_t)Mn * 32;            // [2][512][32]
    unsigned short* w1bf = w0bf + 2 * 512 * 32;              // [2][512][256]

    prep<<<2048, 256, 0, stream>>>(x, wih0f, wih0b, wih1f, wih1b, xb, w0bf, w1bf);

    dim3 gg(1024, 8), gb(256);
    dim3 rg(256, 2), rb(256);

    gemm_tile<32, 1><<<gg, gb, 0, stream>>>(xb, 32, w0bf, gx);
    lstm_rec<0><<<rg, rb, 0, stream>>>(gx, whh0f, whh0b, b0f, b0b, y, y0b, hn, cn);
    gemm_tile<128, 2><<<gg, gb, 0, stream>>>(y0b, 256, w1bf, gx);
    lstm_rec<1><<<rg, rb, 0, stream>>>(gx, whh1f, whh1b, b1f, b1b, y, y0b, hn, cn);
}

// Round 6
// 985.110 us; speedup vs baseline: 1.2063x; 1.1921x over previous
//
#include <hip/hip_runtime.h>
#include <hip/hip_bf16.h>
#include <stdint.h>

#define Bn 256
#define Tn 512
#define Hn 128
#define G4 512   // 4*H
#define Mn (Bn*Tn)

typedef __attribute__((ext_vector_type(8))) short s16x8;
typedef __attribute__((ext_vector_type(8))) unsigned short u16x8;
typedef __attribute__((ext_vector_type(4))) float f32x4;

__device__ __forceinline__ float b2f(unsigned short u) {
    union { unsigned int i; float f; } v; v.i = ((unsigned int)u) << 16; return v.f;
}
__device__ __forceinline__ unsigned short f2b(float f) {
    union { float f; unsigned int i; } v; v.f = f;
    unsigned int x = v.i;
    unsigned int r = (x + 0x7FFFu + ((x >> 16) & 1u)) >> 16;
    return (unsigned short)r;
}
// 8 consecutive fp32 -> bf16 fragment (used by rec for W_hh, once per block)
__device__ __forceinline__ s16x8 cvt8v(const float* p) {
    f32x4 a = *(const f32x4*)p;
    f32x4 b = *(const f32x4*)(p + 4);
    s16x8 r;
    r[0] = (short)f2b(a[0]); r[1] = (short)f2b(a[1]);
    r[2] = (short)f2b(a[2]); r[3] = (short)f2b(a[3]);
    r[4] = (short)f2b(b[0]); r[5] = (short)f2b(b[1]);
    r[6] = (short)f2b(b[2]); r[7] = (short)f2b(b[3]);
    return r;
}
__device__ __forceinline__ float sigm(float x) {
    return __builtin_amdgcn_rcpf(1.f + __expf(-x));
}
__device__ __forceinline__ float tanh_f(float x) {
    return 1.f - 2.f * __builtin_amdgcn_rcpf(1.f + __expf(2.f * x));
}
__device__ __forceinline__ void gload16(const void* gsrc, void* lds) {
    __builtin_amdgcn_global_load_lds(
        (const __attribute__((address_space(1))) unsigned int*)gsrc,
        (__attribute__((address_space(3))) unsigned int*)lds, 16, 0, 0);
}
// LDS-only barrier: waits DS ops but NOT outstanding global loads/stores.
__device__ __forceinline__ void ldsbar() {
    asm volatile("s_waitcnt lgkmcnt(0)\n\ts_barrier" ::: "memory");
}

// ---------------------------------------------------------------------------
// prep: fp32 -> bf16 conversions into d_out scratch (y1 region, written last)
// ---------------------------------------------------------------------------
__global__ __launch_bounds__(256)
void prep(const float* __restrict__ x,
          const float* __restrict__ w0f, const float* __restrict__ w0b,
          const float* __restrict__ w1f, const float* __restrict__ w1b,
          unsigned short* __restrict__ xb,
          unsigned short* __restrict__ w0bf,
          unsigned short* __restrict__ w1bf)
{
    int tid = blockIdx.x * 256 + threadIdx.x;
    int nthr = gridDim.x * 256;
    for (int idx = tid; idx < Mn * 32; idx += nthr) {
        int row = idx >> 5, col = idx & 31;
        xb[idx] = f2b(col < 24 ? x[row * 24 + col] : 0.f);
    }
    for (int idx = tid; idx < 2 * 512 * 32; idx += nthr) {
        int d = idx >> 14, rem = idx & 16383;
        int n = rem >> 5, col = rem & 31;
        const float* w = d ? w0b : w0f;
        w0bf[idx] = f2b(col < 24 ? w[n * 24 + col] : 0.f);
    }
    for (int idx = tid; idx < 2 * 512 * 256; idx += nthr) {
        int d = idx >> 17, rem = idx & 131071;
        const float* w = d ? w1b : w1f;
        w1bf[idx] = f2b(w[rem]);
    }
}

// ---------------------------------------------------------------------------
// Tiled GEMM: gx output in t-BLOCKED layout for the rec kernel:
//   gx[dir][b][tb=te>>3][n=512][tin=te&7], te = dir ? (T-1-t) : t
// (t pre-flipped for dir=1 so rec walks tb,f forward for both dirs).
// Epilogue: 8 x 2B scatter stores per former uint4; each 128B line and each
// 32B sector is written by lanes of a single wave -> no cross-wave merging.
// ---------------------------------------------------------------------------
template<int BK, int KOUT>
__global__ __launch_bounds__(256, 2)
void gemm_tile(const unsigned short* __restrict__ A, int lda,
               const unsigned short* __restrict__ W,   // [2][512][BK*KOUT]
               unsigned short* __restrict__ gx)
{
    constexpr int GR = BK / 8;
    constexpr int SWM = (GR >= 8) ? 7 : (GR - 1);
    constexpr int ASZ = 128 * BK * 2;
    constexpr int GOFF = (BK == 128) ? 0 : 2 * ASZ;
    constexpr int SMEM = 2 * ASZ + ((BK == 128) ? 0 : 4 * 16 * 68 * 4);
    __shared__ char smem[SMEM];
    unsigned short* Atile = (unsigned short*)smem;
    unsigned short* Btile = (unsigned short*)(smem + ASZ);

    const int K = BK * KOUT;
    const int mb = blockIdx.x;
    const int nb = blockIdx.y;
    const int dir = nb >> 2, ncol0 = (nb & 3) * 128;
    const int row0 = mb * 128;
    const unsigned short* Asrc = A + (size_t)row0 * lda;
    const unsigned short* Bsrc = W + (size_t)dir * 512 * K + (size_t)ncol0 * K;
    unsigned short* out = gx + (size_t)dir * Mn * G4;

    const int tid = threadIdx.x;
    const int w = tid >> 6, l = tid & 63;
    const int q = l >> 4, i = l & 15;
    const int wm = w >> 1, wn = w & 1;

    f32x4 acc[4][4];
#pragma unroll
    for (int a = 0; a < 4; ++a)
#pragma unroll
        for (int b = 0; b < 4; ++b) acc[a][b] = f32x4{0.f, 0.f, 0.f, 0.f};

    for (int ko = 0; ko < KOUT; ++ko) {
#pragma unroll
        for (int it = 0; it < (128 * GR) / 256; ++it) {
            int g = it * 256 + tid;
            int row = g / GR, p = g % GR;
            int gi = p ^ (row & SWM);
            gload16(Asrc + (size_t)row * lda + ko * BK + gi * 8,
                    (char*)Atile + g * 16);
        }
#pragma unroll
        for (int it = 0; it < (128 * GR) / 256; ++it) {
            int g = it * 256 + tid;
            int row = g / GR, p = g % GR;
            int gi = p ^ (row & SWM);
            gload16(Bsrc + (size_t)row * K + ko * BK + gi * 8,
                    (char*)Btile + g * 16);
        }
        __syncthreads();   // must drain vmcnt (global_load_lds) — keep full sync
#pragma unroll
        for (int kf = 0; kf < BK / 32; ++kf) {
            s16x8 af[4], bf[4];
#pragma unroll
            for (int mt = 0; mt < 4; ++mt) {
                int ar = wm * 64 + mt * 16 + i;
                int p = (kf * 4 + q) ^ (ar & SWM);
                af[mt] = *(const s16x8*)((char*)Atile + (ar * GR + p) * 16);
            }
#pragma unroll
            for (int nt = 0; nt < 4; ++nt) {
                int br = wn * 64 + nt * 16 + i;
                int p = (kf * 4 + q) ^ (br & SWM);
                bf[nt] = *(const s16x8*)((char*)Btile + (br * GR + p) * 16);
            }
#pragma unroll
            for (int mt = 0; mt < 4; ++mt)
#pragma unroll
                for (int nt = 0; nt < 4; ++nt)
                    acc[mt][nt] = __builtin_amdgcn_mfma_f32_16x16x32_bf16(
                        af[mt], bf[nt], acc[mt][nt], 0, 0, 0);
        }
        __syncthreads();
    }

    float* gbufw = (float*)(smem + GOFF) + w * (16 * 68);
#pragma unroll
    for (int mt = 0; mt < 4; ++mt) {
#pragma unroll
        for (int nt = 0; nt < 4; ++nt)
#pragma unroll
            for (int r = 0; r < 4; ++r)
                gbufw[(q * 4 + r) * 68 + nt * 16 + i] = acc[mt][nt][r];
        __syncthreads();
#pragma unroll
        for (int it2 = 0; it2 < 2; ++it2) {
            int rr = (l >> 3) + it2 * 8;
            int cc = (l & 7) * 8;
            const float* gsrc = gbufw + rr * 68 + cc;
            const int mrow = row0 + wm * 64 + mt * 16 + rr;   // = b*Tn + t
            const int bb = mrow >> 9, t = mrow & 511;
            const int te = dir ? (Tn - 1 - t) : t;
            const int tb = te >> 3, tin = te & 7;
            const int n0 = ncol0 + wn * 64 + cc;
            unsigned short* ob =
                out + ((((size_t)bb * 64 + tb) * 512 + n0) << 3) + tin;
#pragma unroll
            for (int k2 = 0; k2 < 8; ++k2)
                ob[(size_t)k2 * 8] = f2b(gsrc[k2]);
        }
        __syncthreads();
    }
}

// ---------------------------------------------------------------------------
// Recurrent sweep v8 = v7 (blocked gx) + PARITY-DOUBLE-BUFFERED hbuf.
//
// r5 failure root cause: in all single-barrier versions, each wave READS all
// of hbuf and later WRITES its slice between the SAME pair of barriers —
// nothing orders wave A's write(step s) after wave B's read(step s). A
// skewed wave reads next-step h: nondeterministic, sigmoid-damped error
// (v5/v6/v7 absmax drift 0.0047/0.0063/0.0087 vs race-free v3's 0.0039).
// Fix: step s reads h from hbuf[s&1], writes new h to hbuf[(s+1)&1].
// Concurrent reads/writes never share a buffer; the single end-of-step
// barrier provides the only ordering needed (write(s) -> read(s+1)).
// Parity is compile-time (f unrolled; tb*8 even). Zero extra barriers.
// ---------------------------------------------------------------------------
template<int LAYER>
__global__ __launch_bounds__(256, 1)
void lstm_rec(const unsigned short* __restrict__ gx,
              const float* __restrict__ Whf,
              const float* __restrict__ Whb,
              const float* __restrict__ biasf,
              const float* __restrict__ biasb,
              float* __restrict__ y,
              unsigned short* __restrict__ y0b,
              float* __restrict__ hn,
              float* __restrict__ cn)
{
    const int b0  = blockIdx.x * 2;
    const int dir = blockIdx.y;
    const float* Wh   = dir ? Whb : Whf;
    const float* bias = dir ? biasb : biasf;
    const unsigned short* gxd = gx + (size_t)dir * Mn * G4;

    const int tid = threadIdx.x;
    const int w = tid >> 6;          // wave 0..3
    const int l = tid & 63;
    const int q = l >> 4, i = l & 15;
    const int u = q & 1;             // j-subtile select
    const int r = q >> 1;            // batch-in-pair select
    const int j = 32 * w + 16 * u + i;
    const int b = b0 + r;

    // [parity][batch-in-pair][128 h + pad] ; rows stride 320B
    __shared__ __align__(16) unsigned short hbuf[2][2][160];

    for (int idx = tid; idx < 2 * 2 * 160; idx += 256)
        ((unsigned short*)hbuf)[idx] = 0;

    // W_hh fragments: wave w, tile (g,ut): n = 128g + 32w + 16ut + i
    s16x8 wh[4][2][4];
#pragma unroll
    for (int g = 0; g < 4; ++g)
#pragma unroll
        for (int ut = 0; ut < 2; ++ut) {
            int n = 128 * g + 32 * w + 16 * ut + i;
#pragma unroll
            for (int kf = 0; kf < 4; ++kf)
                wh[g][ut][kf] = cvt8v(Wh + (size_t)n * Hn + kf * 32 + q * 8);
        }

    const float bi = bias[j],       bfv = bias[128 + j];
    const float bg = bias[256 + j], bo  = bias[384 + j];
    float c = 0.f, hlast = 0.f;

    // hoisted LDS pointers per parity: A row p -> h[batch p>>3]
    const s16x8* ahp[2][4];
    unsigned short* hwp[2];
#pragma unroll
    for (int par = 0; par < 2; ++par) {
#pragma unroll
        for (int kf = 0; kf < 4; ++kf)
            ahp[par][kf] =
                (const s16x8*)&hbuf[par][i >> 3][kf * 32 + q * 8];
        hwp[par] = &hbuf[par][r][j];
    }

    // blocked gx: addr(tb, g) = gbase + tb*4096 + g*1024 (elements)
    const unsigned short* gbase =
        gxd + (size_t)b * (64 * 512 * 8) + ((size_t)j << 3);

    // y pointers walk the TRUE time index
    const intptr_t ystep = dir ? (intptr_t)-256 : (intptr_t)256;
    const int t0 = dir ? Tn - 1 : 0;
    float* yp = y + ((size_t)b * Tn + t0) * 256 + dir * 128 + j;
    unsigned short* y0p = y0b + ((size_t)b * Tn + t0) * 256 + dir * 128 + j;

    // gx block double-buffer: 4 x (8 bf16) per 8 steps
    u16x8 cur[4], nxt[4];
#pragma unroll
    for (int g = 0; g < 4; ++g)
        cur[g] = *(const u16x8*)(gbase + (size_t)g * 1024);

    __syncthreads();   // once: covers hbuf zero-init

    for (int tb = 0; tb < 64; ++tb) {
        const int tbn = (tb < 63) ? tb + 1 : 63;
#pragma unroll
        for (int f = 0; f < 8; ++f) {
            const int par = f & 1;          // step parity (tb*8 even)

            // latency head: issue the 4 LDS h reads from READ buffer
            s16x8 ah0 = *ahp[par][0], ah1 = *ahp[par][1];
            s16x8 ah2 = *ahp[par][2], ah3 = *ahp[par][3];

            // issue next block's gx loads mid-block (after first consume)
            if (f == 2) {
#pragma unroll
                for (int g = 0; g < 4; ++g)
                    nxt[g] = *(const u16x8*)(gbase + (size_t)tbn * 4096
                                                   + (size_t)g * 1024);
            }

            // pre-combine gx + bias (registers only; f is compile-time)
            const float pi = b2f(cur[0][f]) + bi;
            const float pf = b2f(cur[1][f]) + bfv;
            const float pg = b2f(cur[2][f]) + bg;
            const float po = b2f(cur[3][f]) + bo;

            f32x4 acc[4][2];
#pragma unroll
            for (int g = 0; g < 4; ++g)
#pragma unroll
                for (int ut = 0; ut < 2; ++ut)
                    acc[g][ut] = f32x4{0.f, 0.f, 0.f, 0.f};
#pragma unroll
            for (int g = 0; g < 4; ++g)
#pragma unroll
                for (int ut = 0; ut < 2; ++ut)
                    acc[g][ut] = __builtin_amdgcn_mfma_f32_16x16x32_bf16(
                        ah0, wh[g][ut][0], acc[g][ut], 0, 0, 0);
#pragma unroll
            for (int g = 0; g < 4; ++g)
#pragma unroll
                for (int ut = 0; ut < 2; ++ut)
                    acc[g][ut] = __builtin_amdgcn_mfma_f32_16x16x32_bf16(
                        ah1, wh[g][ut][1], acc[g][ut], 0, 0, 0);
#pragma unroll
            for (int g = 0; g < 4; ++g)
#pragma unroll
                for (int ut = 0; ut < 2; ++ut)
                    acc[g][ut] = __builtin_amdgcn_mfma_f32_16x16x32_bf16(
                        ah2, wh[g][ut][2], acc[g][ut], 0, 0, 0);
#pragma unroll
            for (int g = 0; g < 4; ++g)
#pragma unroll
                for (int ut = 0; ut < 2; ++ut)
                    acc[g][ut] = __builtin_amdgcn_mfma_f32_16x16x32_bf16(
                        ah3, wh[g][ut][3], acc[g][ut], 0, 0, 0);

            // in-lane gate select: element 0 row = q*4, batch = q>>1 (via
            // A-replication); u-subtile select by q&1 -> 1 cndmask per gate
            const float s_i = u ? acc[0][1][0] : acc[0][0][0];
            const float s_f = u ? acc[1][1][0] : acc[1][0][0];
            const float s_g = u ? acc[2][1][0] : acc[2][0][0];
            const float s_o = u ? acc[3][1][0] : acc[3][0][0];

            float g_i = s_i + pi;
            float g_f = s_f + pf;
            float g_g = s_g + pg;
            float g_o = s_o + po;
            float iv = sigm(g_i), fv = sigm(g_f), ov = sigm(g_o);
            float gv = tanh_f(g_g);
            c = fv * c + iv * gv;
            float h = ov * tanh_f(c);
            hlast = h;
            unsigned int hp;
            asm("v_cvt_pk_bf16_f32 %0, %1, %2" : "=v"(hp) : "v"(h), "v"(h));
            unsigned short hb = (unsigned short)hp;
            *hwp[par ^ 1] = hb;                 // WRITE buffer (other parity)
            if (LAYER == 0) *y0p = hb;          // fire-and-forget
            else            *yp  = h;
            yp += ystep; y0p += ystep;

            ldsbar();   // single barrier: write(s) -> read(s+1)
        }
#pragma unroll
        for (int g = 0; g < 4; ++g) cur[g] = nxt[g];
    }

    const int slot = LAYER * 2 + dir;
    hn[((size_t)slot * Bn + b) * Hn + j] = hlast;
    cn[((size_t)slot * Bn + b) * Hn + j] = c;
}

// ---------------------------------------------------------------------------
extern "C" void kernel_launch(void* const* d_in, const int* in_sizes, int n_in,
                              void* d_out, int out_size, void* d_ws, size_t ws_size,
                              hipStream_t stream)
{
    const float* x     = (const float*)d_in[0];
    const float* wih0f = (const float*)d_in[1];
    const float* whh0f = (const float*)d_in[2];
    const float* b0f   = (const float*)d_in[3];
    const float* wih0b = (const float*)d_in[4];
    const float* whh0b = (const float*)d_in[5];
    const float* b0b   = (const float*)d_in[6];
    const float* wih1f = (const float*)d_in[7];
    const float* whh1f = (const float*)d_in[8];
    const float* b1f   = (const float*)d_in[9];
    const float* wih1b = (const float*)d_in[10];
    const float* whh1b = (const float*)d_in[11];
    const float* b1b   = (const float*)d_in[12];

    float* y  = (float*)d_out;                       // [B][T][256] fp32 (final)
    float* hn = y + (size_t)Mn * 256;                // [4][B][128]
    float* cn = hn + (size_t)4 * Bn * Hn;            // [4][B][128]
    unsigned short* gx = (unsigned short*)d_ws;      // [2][B][64][512][8] bf16

    unsigned short* scr  = (unsigned short*)d_out;
    unsigned short* y0b  = scr;                              // [M][256] bf16
    unsigned short* xb   = scr + (size_t)Mn * 256;           // [M][32]
    unsigned short* w0bf = xb  + (size_t)Mn * 32;            // [2][512][32]
    unsigned short* w1bf = w0bf + 2 * 512 * 32;              // [2][512][256]

    prep<<<2048, 256, 0, stream>>>(x, wih0f, wih0b, wih1f, wih1b, xb, w0bf, w1bf);

    dim3 gg(1024, 8), gb(256);
    dim3 rg(128, 2), rb(256);

    gemm_tile<32, 1><<<gg, gb, 0, stream>>>(xb, 32, w0bf, gx);
    lstm_rec<0><<<rg, rb, 0, stream>>>(gx, whh0f, whh0b, b0f, b0b, y, y0b, hn, cn);
    gemm_tile<128, 2><<<gg, gb, 0, stream>>>(y0b, 256, w1bf, gx);
    lstm_rec<1><<<rg, rb, 0, stream>>>(gx, whh1f, whh1b, b1f, b1b, y, y0b, hn, cn);
}

// Round 7
// 852.295 us; speedup vs baseline: 1.3943x; 1.1558x over previous
//
#include <hip/hip_runtime.h>
#include <hip/hip_bf16.h>
#include <stdint.h>

#define Bn 256
#define Tn 512
#define Hn 128
#define G4 512   // 4*H
#define Mn (Bn*Tn)

typedef __attribute__((ext_vector_type(8))) short s16x8;
typedef __attribute__((ext_vector_type(8))) unsigned short u16x8;
typedef __attribute__((ext_vector_type(4))) float f32x4;

__device__ __forceinline__ float b2f(unsigned short u) {
    union { unsigned int i; float f; } v; v.i = ((unsigned int)u) << 16; return v.f;
}
__device__ __forceinline__ unsigned short f2b(float f) {
    union { float f; unsigned int i; } v; v.f = f;
    unsigned int x = v.i;
    unsigned int r = (x + 0x7FFFu + ((x >> 16) & 1u)) >> 16;
    return (unsigned short)r;
}
// packed fp32x2 -> bf16x2 (RNE)
__device__ __forceinline__ unsigned int pk2(float a, float b) {
    __hip_bfloat162 t = __float22bfloat162_rn(make_float2(a, b));
    union { __hip_bfloat162 v; unsigned int u; } c; c.v = t; return c.u;
}
// 8 consecutive fp32 -> bf16 fragment (used by rec for W_hh, once per block)
__device__ __forceinline__ s16x8 cvt8v(const float* p) {
    f32x4 a = *(const f32x4*)p;
    f32x4 b = *(const f32x4*)(p + 4);
    s16x8 r;
    r[0] = (short)f2b(a[0]); r[1] = (short)f2b(a[1]);
    r[2] = (short)f2b(a[2]); r[3] = (short)f2b(a[3]);
    r[4] = (short)f2b(b[0]); r[5] = (short)f2b(b[1]);
    r[6] = (short)f2b(b[2]); r[7] = (short)f2b(b[3]);
    return r;
}
__device__ __forceinline__ float sigm(float x) {
    return __builtin_amdgcn_rcpf(1.f + __expf(-x));
}
__device__ __forceinline__ float tanh_f(float x) {
    return 1.f - 2.f * __builtin_amdgcn_rcpf(1.f + __expf(2.f * x));
}
__device__ __forceinline__ void gload16(const void* gsrc, void* lds) {
    __builtin_amdgcn_global_load_lds(
        (const __attribute__((address_space(1))) unsigned int*)gsrc,
        (__attribute__((address_space(3))) unsigned int*)lds, 16, 0, 0);
}
// LDS-only barrier: waits DS ops but NOT outstanding global loads/stores.
__device__ __forceinline__ void ldsbar() {
    asm volatile("s_waitcnt lgkmcnt(0)\n\ts_barrier" ::: "memory");
}

// ---------------------------------------------------------------------------
// prep: fp32 -> bf16 conversions into d_out scratch (y1 region, written last)
// ---------------------------------------------------------------------------
__global__ __launch_bounds__(256)
void prep(const float* __restrict__ x,
          const float* __restrict__ w0f, const float* __restrict__ w0b,
          const float* __restrict__ w1f, const float* __restrict__ w1b,
          unsigned short* __restrict__ xb,
          unsigned short* __restrict__ w0bf,
          unsigned short* __restrict__ w1bf)
{
    int tid = blockIdx.x * 256 + threadIdx.x;
    int nthr = gridDim.x * 256;
    for (int idx = tid; idx < Mn * 32; idx += nthr) {
        int row = idx >> 5, col = idx & 31;
        xb[idx] = f2b(col < 24 ? x[row * 24 + col] : 0.f);
    }
    for (int idx = tid; idx < 2 * 512 * 32; idx += nthr) {
        int d = idx >> 14, rem = idx & 16383;
        int n = rem >> 5, col = rem & 31;
        const float* w = d ? w0b : w0f;
        w0bf[idx] = f2b(col < 24 ? w[n * 24 + col] : 0.f);
    }
    for (int idx = tid; idx < 2 * 512 * 256; idx += nthr) {
        int d = idx >> 17, rem = idx & 131071;
        const float* w = d ? w1b : w1f;
        w1bf[idx] = f2b(w[rem]);
    }
}

// ---------------------------------------------------------------------------
// Tiled GEMM: gx output in t-BLOCKED layout for the rec kernel:
//   gx[dir][b][tb=te>>3][n=512][tin=te&7], te = dir ? (T-1-t) : t
// Epilogue v9: COLUMN-gather — lane owns one n-column, 8 t-rows (one tb,
// t-base 8-aligned so all 8 land in one [tin] run) -> ONE 16B store/lane,
// 1024B contiguous per wave. Same instr count as the r1 wide epilogue;
// fixes r6's 8x2B scatter regression (~167 us).
// ---------------------------------------------------------------------------
template<int BK, int KOUT>
__global__ __launch_bounds__(256, 2)
void gemm_tile(const unsigned short* __restrict__ A, int lda,
               const unsigned short* __restrict__ W,   // [2][512][BK*KOUT]
               unsigned short* __restrict__ gx)
{
    constexpr int GR = BK / 8;
    constexpr int SWM = (GR >= 8) ? 7 : (GR - 1);
    constexpr int ASZ = 128 * BK * 2;
    constexpr int GOFF = (BK == 128) ? 0 : 2 * ASZ;
    constexpr int SMEM = 2 * ASZ + ((BK == 128) ? 0 : 4 * 16 * 68 * 4);
    __shared__ char smem[SMEM];
    unsigned short* Atile = (unsigned short*)smem;
    unsigned short* Btile = (unsigned short*)(smem + ASZ);

    const int K = BK * KOUT;
    const int mb = blockIdx.x;
    const int nb = blockIdx.y;
    const int dir = nb >> 2, ncol0 = (nb & 3) * 128;
    const int row0 = mb * 128;
    const unsigned short* Asrc = A + (size_t)row0 * lda;
    const unsigned short* Bsrc = W + (size_t)dir * 512 * K + (size_t)ncol0 * K;
    unsigned short* out = gx + (size_t)dir * Mn * G4;

    const int tid = threadIdx.x;
    const int w = tid >> 6, l = tid & 63;
    const int q = l >> 4, i = l & 15;
    const int wm = w >> 1, wn = w & 1;

    f32x4 acc[4][4];
#pragma unroll
    for (int a = 0; a < 4; ++a)
#pragma unroll
        for (int b = 0; b < 4; ++b) acc[a][b] = f32x4{0.f, 0.f, 0.f, 0.f};

    for (int ko = 0; ko < KOUT; ++ko) {
#pragma unroll
        for (int it = 0; it < (128 * GR) / 256; ++it) {
            int g = it * 256 + tid;
            int row = g / GR, p = g % GR;
            int gi = p ^ (row & SWM);
            gload16(Asrc + (size_t)row * lda + ko * BK + gi * 8,
                    (char*)Atile + g * 16);
        }
#pragma unroll
        for (int it = 0; it < (128 * GR) / 256; ++it) {
            int g = it * 256 + tid;
            int row = g / GR, p = g % GR;
            int gi = p ^ (row & SWM);
            gload16(Bsrc + (size_t)row * K + ko * BK + gi * 8,
                    (char*)Btile + g * 16);
        }
        __syncthreads();   // must drain vmcnt (global_load_lds) — keep full sync
#pragma unroll
        for (int kf = 0; kf < BK / 32; ++kf) {
            s16x8 af[4], bf[4];
#pragma unroll
            for (int mt = 0; mt < 4; ++mt) {
                int ar = wm * 64 + mt * 16 + i;
                int p = (kf * 4 + q) ^ (ar & SWM);
                af[mt] = *(const s16x8*)((char*)Atile + (ar * GR + p) * 16);
            }
#pragma unroll
            for (int nt = 0; nt < 4; ++nt) {
                int br = wn * 64 + nt * 16 + i;
                int p = (kf * 4 + q) ^ (br & SWM);
                bf[nt] = *(const s16x8*)((char*)Btile + (br * GR + p) * 16);
            }
#pragma unroll
            for (int mt = 0; mt < 4; ++mt)
#pragma unroll
                for (int nt = 0; nt < 4; ++nt)
                    acc[mt][nt] = __builtin_amdgcn_mfma_f32_16x16x32_bf16(
                        af[mt], bf[nt], acc[mt][nt], 0, 0, 0);
        }
        __syncthreads();
    }

    float* gbufw = (float*)(smem + GOFF) + w * (16 * 68);
#pragma unroll
    for (int mt = 0; mt < 4; ++mt) {
#pragma unroll
        for (int nt = 0; nt < 4; ++nt)
#pragma unroll
            for (int r = 0; r < 4; ++r)
                gbufw[(q * 4 + r) * 68 + nt * 16 + i] = acc[mt][nt][r];
        __syncthreads();
        // column-gather: lane l = n-column; rg = 8-row (t) group
#pragma unroll
        for (int rg = 0; rg < 2; ++rg) {
            const float* gcol = gbufw + rg * 8 * 68 + l;
            float v[8];
#pragma unroll
            for (int k2 = 0; k2 < 8; ++k2)
                v[k2] = gcol[k2 * 68];
            const int mrow0 = row0 + wm * 64 + mt * 16 + rg * 8;  // 8-aligned
            const int bb = mrow0 >> 9, tB = mrow0 & 511;
            const int te0 = dir ? (Tn - 1 - tB - 7) : tB;          // tb base
            const int tb = te0 >> 3;
            const int n0 = ncol0 + wn * 64 + l;
            uint4 pv;
            if (!dir) {
                pv.x = pk2(v[0], v[1]); pv.y = pk2(v[2], v[3]);
                pv.z = pk2(v[4], v[5]); pv.w = pk2(v[6], v[7]);
            } else {   // tin = 7 - k2
                pv.x = pk2(v[7], v[6]); pv.y = pk2(v[5], v[4]);
                pv.z = pk2(v[3], v[2]); pv.w = pk2(v[1], v[0]);
            }
            *(uint4*)(out + ((((size_t)bb * 64 + tb) * 512 + n0) << 3)) = pv;
        }
        __syncthreads();
    }
}

// ---------------------------------------------------------------------------
// Recurrent sweep v8 (UNCHANGED from r6, passed): blocked gx loads +
// parity-double-buffered hbuf (race-free), single ldsbar per step.
// ---------------------------------------------------------------------------
template<int LAYER>
__global__ __launch_bounds__(256, 1)
void lstm_rec(const unsigned short* __restrict__ gx,
              const float* __restrict__ Whf,
              const float* __restrict__ Whb,
              const float* __restrict__ biasf,
              const float* __restrict__ biasb,
              float* __restrict__ y,
              unsigned short* __restrict__ y0b,
              float* __restrict__ hn,
              float* __restrict__ cn)
{
    const int b0  = blockIdx.x * 2;
    const int dir = blockIdx.y;
    const float* Wh   = dir ? Whb : Whf;
    const float* bias = dir ? biasb : biasf;
    const unsigned short* gxd = gx + (size_t)dir * Mn * G4;

    const int tid = threadIdx.x;
    const int w = tid >> 6;          // wave 0..3
    const int l = tid & 63;
    const int q = l >> 4, i = l & 15;
    const int u = q & 1;             // j-subtile select
    const int r = q >> 1;            // batch-in-pair select
    const int j = 32 * w + 16 * u + i;
    const int b = b0 + r;

    // [parity][batch-in-pair][128 h + pad] ; rows stride 320B
    __shared__ __align__(16) unsigned short hbuf[2][2][160];

    for (int idx = tid; idx < 2 * 2 * 160; idx += 256)
        ((unsigned short*)hbuf)[idx] = 0;

    // W_hh fragments: wave w, tile (g,ut): n = 128g + 32w + 16ut + i
    s16x8 wh[4][2][4];
#pragma unroll
    for (int g = 0; g < 4; ++g)
#pragma unroll
        for (int ut = 0; ut < 2; ++ut) {
            int n = 128 * g + 32 * w + 16 * ut + i;
#pragma unroll
            for (int kf = 0; kf < 4; ++kf)
                wh[g][ut][kf] = cvt8v(Wh + (size_t)n * Hn + kf * 32 + q * 8);
        }

    const float bi = bias[j],       bfv = bias[128 + j];
    const float bg = bias[256 + j], bo  = bias[384 + j];
    float c = 0.f, hlast = 0.f;

    // hoisted LDS pointers per parity: A row p -> h[batch p>>3]
    const s16x8* ahp[2][4];
    unsigned short* hwp[2];
#pragma unroll
    for (int par = 0; par < 2; ++par) {
#pragma unroll
        for (int kf = 0; kf < 4; ++kf)
            ahp[par][kf] =
                (const s16x8*)&hbuf[par][i >> 3][kf * 32 + q * 8];
        hwp[par] = &hbuf[par][r][j];
    }

    // blocked gx: addr(tb, g) = gbase + tb*4096 + g*1024 (elements)
    const unsigned short* gbase =
        gxd + (size_t)b * (64 * 512 * 8) + ((size_t)j << 3);

    // y pointers walk the TRUE time index
    const intptr_t ystep = dir ? (intptr_t)-256 : (intptr_t)256;
    const int t0 = dir ? Tn - 1 : 0;
    float* yp = y + ((size_t)b * Tn + t0) * 256 + dir * 128 + j;
    unsigned short* y0p = y0b + ((size_t)b * Tn + t0) * 256 + dir * 128 + j;

    // gx block double-buffer: 4 x (8 bf16) per 8 steps
    u16x8 cur[4], nxt[4];
#pragma unroll
    for (int g = 0; g < 4; ++g)
        cur[g] = *(const u16x8*)(gbase + (size_t)g * 1024);

    __syncthreads();   // once: covers hbuf zero-init

    for (int tb = 0; tb < 64; ++tb) {
        const int tbn = (tb < 63) ? tb + 1 : 63;
#pragma unroll
        for (int f = 0; f < 8; ++f) {
            const int par = f & 1;          // step parity (tb*8 even)

            // latency head: issue the 4 LDS h reads from READ buffer
            s16x8 ah0 = *ahp[par][0], ah1 = *ahp[par][1];
            s16x8 ah2 = *ahp[par][2], ah3 = *ahp[par][3];

            // issue next block's gx loads mid-block (after first consume)
            if (f == 2) {
#pragma unroll
                for (int g = 0; g < 4; ++g)
                    nxt[g] = *(const u16x8*)(gbase + (size_t)tbn * 4096
                                                   + (size_t)g * 1024);
            }

            // pre-combine gx + bias (registers only; f is compile-time)
            const float pi = b2f(cur[0][f]) + bi;
            const float pf = b2f(cur[1][f]) + bfv;
            const float pg = b2f(cur[2][f]) + bg;
            const float po = b2f(cur[3][f]) + bo;

            f32x4 acc[4][2];
#pragma unroll
            for (int g = 0; g < 4; ++g)
#pragma unroll
                for (int ut = 0; ut < 2; ++ut)
                    acc[g][ut] = f32x4{0.f, 0.f, 0.f, 0.f};
#pragma unroll
            for (int g = 0; g < 4; ++g)
#pragma unroll
                for (int ut = 0; ut < 2; ++ut)
                    acc[g][ut] = __builtin_amdgcn_mfma_f32_16x16x32_bf16(
                        ah0, wh[g][ut][0], acc[g][ut], 0, 0, 0);
#pragma unroll
            for (int g = 0; g < 4; ++g)
#pragma unroll
                for (int ut = 0; ut < 2; ++ut)
                    acc[g][ut] = __builtin_amdgcn_mfma_f32_16x16x32_bf16(
                        ah1, wh[g][ut][1], acc[g][ut], 0, 0, 0);
#pragma unroll
            for (int g = 0; g < 4; ++g)
#pragma unroll
                for (int ut = 0; ut < 2; ++ut)
                    acc[g][ut] = __builtin_amdgcn_mfma_f32_16x16x32_bf16(
                        ah2, wh[g][ut][2], acc[g][ut], 0, 0, 0);
#pragma unroll
            for (int g = 0; g < 4; ++g)
#pragma unroll
                for (int ut = 0; ut < 2; ++ut)
                    acc[g][ut] = __builtin_amdgcn_mfma_f32_16x16x32_bf16(
                        ah3, wh[g][ut][3], acc[g][ut], 0, 0, 0);

            // in-lane gate select: element 0 row = q*4, batch = q>>1 (via
            // A-replication); u-subtile select by q&1 -> 1 cndmask per gate
            const float s_i = u ? acc[0][1][0] : acc[0][0][0];
            const float s_f = u ? acc[1][1][0] : acc[1][0][0];
            const float s_g = u ? acc[2][1][0] : acc[2][0][0];
            const float s_o = u ? acc[3][1][0] : acc[3][0][0];

            float g_i = s_i + pi;
            float g_f = s_f + pf;
            float g_g = s_g + pg;
            float g_o = s_o + po;
            float iv = sigm(g_i), fv = sigm(g_f), ov = sigm(g_o);
            float gv = tanh_f(g_g);
            c = fv * c + iv * gv;
            float h = ov * tanh_f(c);
            hlast = h;
            unsigned int hp;
            asm("v_cvt_pk_bf16_f32 %0, %1, %2" : "=v"(hp) : "v"(h), "v"(h));
            unsigned short hb = (unsigned short)hp;
            *hwp[par ^ 1] = hb;                 // WRITE buffer (other parity)
            if (LAYER == 0) *y0p = hb;          // fire-and-forget
            else            *yp  = h;
            yp += ystep; y0p += ystep;

            ldsbar();   // single barrier: write(s) -> read(s+1)
        }
#pragma unroll
        for (int g = 0; g < 4; ++g) cur[g] = nxt[g];
    }

    const int slot = LAYER * 2 + dir;
    hn[((size_t)slot * Bn + b) * Hn + j] = hlast;
    cn[((size_t)slot * Bn + b) * Hn + j] = c;
}

// ---------------------------------------------------------------------------
extern "C" void kernel_launch(void* const* d_in, const int* in_sizes, int n_in,
                              void* d_out, int out_size, void* d_ws, size_t ws_size,
                              hipStream_t stream)
{
    const float* x     = (const float*)d_in[0];
    const float* wih0f = (const float*)d_in[1];
    const float* whh0f = (const float*)d_in[2];
    const float* b0f   = (const float*)d_in[3];
    const float* wih0b = (const float*)d_in[4];
    const float* whh0b = (const float*)d_in[5];
    const float* b0b   = (const float*)d_in[6];
    const float* wih1f = (const float*)d_in[7];
    const float* whh1f = (const float*)d_in[8];
    const float* b1f   = (const float*)d_in[9];
    const float* wih1b = (const float*)d_in[10];
    const float* whh1b = (const float*)d_in[11];
    const float* b1b   = (const float*)d_in[12];

    float* y  = (float*)d_out;                       // [B][T][256] fp32 (final)
    float* hn = y + (size_t)Mn * 256;                // [4][B][128]
    float* cn = hn + (size_t)4 * Bn * Hn;            // [4][B][128]
    unsigned short* gx = (unsigned short*)d_ws;      // [2][B][64][512][8] bf16

    unsigned short* scr  = (unsigned short*)d_out;
    unsigned short* y0b  = scr;                              // [M][256] bf16
    unsigned short* xb   = scr + (size_t)Mn * 256;           // [M][32]
    unsigned short* w0bf = xb  + (size_t)Mn * 32;            // [2][512][32]
    unsigned short* w1bf = w0bf + 2 * 512 * 32;              // [2][512][256]

    prep<<<2048, 256, 0, stream>>>(x, wih0f, wih0b, wih1f, wih1b, xb, w0bf, w1bf);

    dim3 gg(1024, 8), gb(256);
    dim3 rg(128, 2), rb(256);

    gemm_tile<32, 1><<<gg, gb, 0, stream>>>(xb, 32, w0bf, gx);
    lstm_rec<0><<<rg, rb, 0, stream>>>(gx, whh0f, whh0b, b0f, b0b, y, y0b, hn, cn);
    gemm_tile<128, 2><<<gg, gb, 0, stream>>>(y0b, 256, w1bf, gx);
    lstm_rec<1><<<rg, rb, 0, stream>>>(gx, whh1f, whh1b, b1f, b1b, y, y0b, hn, cn);
}